// Round 4
// baseline (281.288 us; speedup 1.0000x reference)
//
#include <hip/hip_runtime.h>

typedef float f32x4 __attribute__((ext_vector_type(4)));

#define B_  512
#define T_  64
#define N_  30
#define FIN 512
#define D_  256
#define C_  7
#define NN  (N_ * N_)   // 900

// LDS layout (floats):
//   [0, 16384)      realS[32][512] (rows 30,31 zeroed) -- reused as xwS[32][256] ([0,8192))
//   [16384, 17408)  adjS[32][32]   (rows 0..29 used; cols 30,31 zeroed)
//   [17408, 17536)  scoreS[4][32]
//   [17536, 17568)  sumS[32]
//   [17568, 17576)  logitS[8]
__global__ __launch_bounds__(512, 4)
void digcn_fused(const float* __restrict__ real,
                 const float* __restrict__ gs,
                 const float* __restrict__ W,
                 const float* __restrict__ conv_bias,
                 const float* __restrict__ pool_w,
                 const float* __restrict__ pool_b,
                 const float* __restrict__ head_w,
                 const float* __restrict__ head_b,
                 float* __restrict__ out)
{
    __shared__ __align__(16) float lds[17600];
    float* adjS   = lds + 16384;
    float* scoreS = lds + 17408;
    float* sumS   = lds + 17536;
    float* logitS = lds + 17568;

    const int tid = threadIdx.x;
    const int b   = blockIdx.x;
    const int w   = tid >> 6;        // wave 0..7
    const int l   = tid & 63;
    const int kq  = w & 3;           // K-quarter: f in [kq*128, kq*128+128)
    const int rg  = w >> 2;          // row-group: rows rg*16 .. rg*16+15
    const int rh  = l >> 5;          // row-half within wave
    const int cg  = l & 31;          // col-group
    const int r0  = rg * 16 + rh * 8;    // thread's 8 rows start
    const int c0  = cg * 8;              // thread's 8 cols start

    const float* realb = real + (size_t)b * (N_ * FIN);
    const float* gsb   = gs   + (size_t)b * (T_ * NN);
    const float* WQ    = W + (size_t)(kq * 128) * D_ + c0;

    // ---- gs prefetch for slices 0,1 (issue before staging) ----
    float pa0 = gsb[tid];
    float pa1 = (tid + 512 < NN) ? gsb[tid + 512] : 0.f;
    float pb0 = gsb[NN + tid];
    float pb1 = (tid + 512 < NN) ? gsb[NN + tid + 512] : 0.f;

    // ---- P0: stage real[b] into LDS rows 0..29, zero rows 30,31 ----
    #pragma unroll
    for (int it = 0; it < 8; ++it) {
        int idx = (it * 512 + tid) * 4;
        f32x4 v = (f32x4){0.f, 0.f, 0.f, 0.f};
        if (idx < N_ * FIN) v = *(const f32x4*)(realb + idx);
        *(f32x4*)(lds + idx) = v;
    }
    __syncthreads();

    // ---- P1: xw GEMM, thread = 8 rows x 8 cols x K=128; gs mean interleaved ----
    f32x4 acc[8][2];
    #pragma unroll
    for (int rr = 0; rr < 8; ++rr) {
        acc[rr][0] = (f32x4){0.f, 0.f, 0.f, 0.f};
        acc[rr][1] = (f32x4){0.f, 0.f, 0.f, 0.f};
    }
    float adj0 = 0.f, adj1 = 0.f;

    for (int it = 0; it < 32; ++it) {           // 4 f-values per iteration
        // gs prefetch for slices 2it+2, 2it+3
        float na0 = 0.f, na1 = 0.f, nb0 = 0.f, nb1 = 0.f;
        if (it < 31) {
            const float* g2 = gsb + (2 * it + 2) * NN;
            na0 = g2[tid];
            nb0 = g2[NN + tid];
            if (tid + 512 < NN) { na1 = g2[tid + 512]; nb1 = g2[NN + tid + 512]; }
        }
        // W loads: 4 rows of this K-quarter, this thread's 8 cols
        const float* Wit = WQ + it * 4 * D_;
        f32x4 wv[4][2];
        #pragma unroll
        for (int ff = 0; ff < 4; ++ff) {
            wv[ff][0] = *(const f32x4*)(Wit + ff * D_);
            wv[ff][1] = *(const f32x4*)(Wit + ff * D_ + 4);
        }
        // rv broadcast (2 addresses per inst: rh halves -> free 2-way) + FMAs
        #pragma unroll
        for (int rr = 0; rr < 8; ++rr) {
            f32x4 rv = *(const f32x4*)(lds + (r0 + rr) * FIN + kq * 128 + it * 4);
            #pragma unroll
            for (int ff = 0; ff < 4; ++ff) {
                acc[rr][0] += wv[ff][0] * rv[ff];
                acc[rr][1] += wv[ff][1] * rv[ff];
            }
        }
        adj0 += pa0 + pb0;
        adj1 += pa1 + pb1;
        pa0 = na0; pa1 = na1; pb0 = nb0; pb1 = nb1;
    }
    __syncthreads();   // all realS reads done; lds[0,8192) becomes xwS[32][256]

    // ---- P2a: adj mean into adjS (separate LDS region) ----
    {
        int i = tid / N_, j = tid - i * N_;          // tid < 900 always
        adjS[i * 32 + j] = adj0 * (1.f / (float)T_);
        int e = tid + 512;
        if (e < NN) {
            int i2 = e / N_, j2 = e - i2 * N_;
            adjS[i2 * 32 + j2] = adj1 * (1.f / (float)T_);
        }
    }
    if (tid < 60) adjS[(tid >> 1) * 32 + 30 + (tid & 1)] = 0.f;   // zero pad cols

    // ---- P2b: staged K-quarter reduction into xwS ----
    float* xwS = lds;
    #pragma unroll
    for (int step = 0; step < 4; ++step) {
        if (kq == step) {
            #pragma unroll
            for (int rr = 0; rr < 8; ++rr) {
                float* p = xwS + (r0 + rr) * D_ + c0;
                if (step == 0) {
                    *(f32x4*)p       = acc[rr][0];
                    *(f32x4*)(p + 4) = acc[rr][1];
                } else {
                    f32x4 t0 = *(const f32x4*)p;
                    f32x4 t1 = *(const f32x4*)(p + 4);
                    *(f32x4*)p       = t0 + acc[rr][0];
                    *(f32x4*)(p + 4) = t1 + acc[rr][1];
                }
            }
        }
        __syncthreads();
    }
    // xwS rows 30,31 are zero (realS rows 30,31 were zeroed)

    // ---- P3: agg = adj^T @ xw, ReLU, pool (threads 0..255, thread owns d) ----
    if (tid < D_) {
        float xcol[N_];
        #pragma unroll
        for (int i = 0; i < N_; ++i) xcol[i] = xwS[i * D_ + tid];   // stride-1 lanes: conflict-free
        const float bias = conv_bias[tid];
        const float pw   = pool_w[tid];

        #pragma unroll
        for (int j0 = 0; j0 < N_ + 2; j0 += 4) {
            f32x4 agg = (f32x4){0.f, 0.f, 0.f, 0.f};
            #pragma unroll
            for (int i = 0; i < N_; ++i) {
                f32x4 a4 = *(const f32x4*)(adjS + i * 32 + j0);     // uniform broadcast
                agg += a4 * xcol[i];
            }
            #pragma unroll
            for (int c = 0; c < 4; ++c) {
                if (j0 + c < N_) {
                    float h = agg[c] + bias;
                    h = h > 0.f ? h : 0.f;
                    float v = h * pw;
                    #pragma unroll
                    for (int m = 32; m >= 1; m >>= 1) v += __shfl_xor(v, m, 64);
                    if (l == 0) scoreS[w * 32 + j0 + c] = v;
                }
            }
        }
    }
    __syncthreads();

    // ---- P4: combine waves, head matmul, softmax ----
    if (tid < N_)
        sumS[tid] = scoreS[tid] + scoreS[32 + tid] + scoreS[64 + tid] + scoreS[96 + tid]
                  + pool_b[0];
    __syncthreads();
    if (tid < C_) {
        float lg = head_b[tid];
        #pragma unroll
        for (int j = 0; j < N_; ++j) lg += sumS[j] * head_w[tid * N_ + j];
        logitS[tid] = lg;
    }
    __syncthreads();
    if (tid < C_) {
        float m = logitS[0];
        #pragma unroll
        for (int c = 1; c < C_; ++c) m = fmaxf(m, logitS[c]);
        float s = 0.f;
        #pragma unroll
        for (int c = 0; c < C_; ++c) s += expf(logitS[c] - m);
        out[b * C_ + tid] = expf(logitS[tid] - m) / s;
    }
}

extern "C" void kernel_launch(void* const* d_in, const int* in_sizes, int n_in,
                              void* d_out, int out_size, void* d_ws, size_t ws_size,
                              hipStream_t stream) {
    const float* real      = (const float*)d_in[0];
    // d_in[1] (imag) is unused by the forward pass
    const float* gs        = (const float*)d_in[2];
    const float* W         = (const float*)d_in[3];
    const float* conv_bias = (const float*)d_in[4];
    const float* pool_w    = (const float*)d_in[5];
    const float* pool_b    = (const float*)d_in[6];
    const float* head_w    = (const float*)d_in[7];
    const float* head_b    = (const float*)d_in[8];
    float* outp            = (float*)d_out;

    digcn_fused<<<dim3(B_), dim3(512), 0, stream>>>(
        real, gs, W, conv_bias, pool_w, pool_b, head_w, head_b, outp);
}